// Round 1
// 480.517 us; speedup vs baseline: 1.1482x; 1.1482x over previous
//
#include <hip/hip_runtime.h>

// ContactNet grasp construction — memory-bound elementwise kernel.
// Inputs (fp32): points[N,3], z1[N,3], z2[N,3], s[N], w[N]
// Outputs (fp32, concatenated flat): points[N*3] | grasps[N*16] | sigmoid(s)[N] | relu(w)[N]
//
// R3 coalescing overhaul: all global traffic is now 1024B/wave coalesced.
//  - xyz inputs staged via LDS (coalesced f4 load -> LDS -> stride-3 scalar reads,
//    2-way bank aliasing = free). pts staging load doubles as the pass-through copy.
//  - grasp stores staged via a 16KB LDS buffer with XOR swizzle (k ^ ((tid>>1)&3)),
//    conflict-free on both ds_write_b128 and ds_read_b128 sides, then stored as
//    4 coalesced dwordx4/thread (was: 16 stores at 256B lane stride = 4x L2
//    write-request amplification on the 268MB grasp stream).
//
// Dtype forensics (prior session): fp32 in, fp32 out.

typedef float floatx4 __attribute__((ext_vector_type(4)));

constexpr long N_POINTS    = 4194304;
constexpr long GRASP_BASE4 = N_POINTS * 3 / 4;    // float4 index of grasps section
constexpr long S_BASE4     = N_POINTS * 19 / 4;   // float4 index of sigmoid(s) section
constexpr long W_BASE4     = N_POINTS * 20 / 4;   // float4 index of relu(w) section

__global__ __launch_bounds__(256) void contactnet_kernel(
    const floatx4* __restrict__ pts,
    const floatx4* __restrict__ z1v,
    const floatx4* __restrict__ z2v,
    const floatx4* __restrict__ sv,
    const floatx4* __restrict__ wv,
    floatx4* __restrict__ out)
{
    // 1024 points per block: 3 staged xyz arrays (12KB each) + 16KB grasp staging
    // = 52 KB -> 3 blocks/CU (12 waves/CU), plenty for a streaming kernel.
    __shared__ float   lds_p[3072];
    __shared__ float   lds_1[3072];
    __shared__ float   lds_2[3072];
    __shared__ floatx4 lds_g[1024];

    const int  tid = threadIdx.x;
    const long bid = blockIdx.x;
    const long inb = bid * 768;            // this block's float4 base in pts/z1/z2

    // ---- coalesced input staging; pts load doubles as the pass-through copy ----
#pragma unroll
    for (int i = 0; i < 3; ++i) {
        const long idx = inb + i * 256 + tid;
        const floatx4 vp = pts[idx];
        out[idx] = vp;                                                  // points copy
        *reinterpret_cast<floatx4*>(&lds_p[(i * 256 + tid) * 4]) = vp;
        *reinterpret_cast<floatx4*>(&lds_1[(i * 256 + tid) * 4]) = z1v[idx];
        *reinterpret_cast<floatx4*>(&lds_2[(i * 256 + tid) * 4]) = z2v[idx];
    }

    // ---- s / w tails: already coalesced, independent of grasp point mapping ----
    const long swb = bid * 256 + tid;
    const floatx4 s4 = sv[swb];
    const floatx4 w4 = wv[swb];
    floatx4 sres, wres;
#pragma unroll
    for (int c = 0; c < 4; ++c) {
        sres[c] = 1.0f / (1.0f + __expf(-s4[c]));
        wres[c] = fmaxf(w4[c], 0.0f);
    }
    out[S_BASE4 + swb] = sres;
    out[W_BASE4 + swb] = wres;

    __syncthreads();

    const float* __restrict__ wsc = reinterpret_cast<const float*>(wv);

    // ---- 4 rounds of 256 grasps: compute -> swizzled LDS stage -> coalesced store
#pragma unroll
    for (int j = 0; j < 4; ++j) {
        const int q  = j * 256 + tid;      // local point index within block
        const int b3 = q * 3;

        const float px  = lds_p[b3], py  = lds_p[b3 + 1], pz  = lds_p[b3 + 2];
        const float z1x = lds_1[b3], z1y = lds_1[b3 + 1], z1z = lds_1[b3 + 2];
        const float z2x = lds_2[b3], z2y = lds_2[b3 + 1], z2z = lds_2[b3 + 2];
        const float wf  = wsc[bid * 1024 + q];   // coalesced dword, L1/L2-hot (just loaded)

        // base_dirs = z1 / ||z1||  (== x_col; re-normalizing a unit vector is identity)
        const float rn1 = rsqrtf(z1x * z1x + z1y * z1y + z1z * z1z);
        const float bx = z1x * rn1, by = z1y * rn1, bz = z1z * rn1;

        // approach_dirs = (z2 - <b,z2> b) / ||z2||
        const float inner = bx * z2x + by * z2y + bz * z2z;
        const float rn2 = rsqrtf(z2x * z2x + z2y * z2y + z2z * z2z);
        const float ax = (z2x - inner * bx) * rn2;
        const float ay = (z2y - inner * by) * rn2;
        const float az = (z2z - inner * bz) * rn2;

        // z_col = normalize(approach_dirs)
        const float rna = rsqrtf(ax * ax + ay * ay + az * az);
        const float zx = ax * rna, zy = ay * rna, zz = az * rna;

        // y_col = normalize(cross(z_col, x_col))
        const float cx = zy * bz - zz * by;
        const float cy = zz * bx - zx * bz;
        const float cz = zx * by - zy * bx;
        const float rnc = rsqrtf(cx * cx + cy * cy + cz * cz);
        const float yx = cx * rnc, yy = cy * rnc, yz = cz * rnc;

        // t_col = p + (w/2) x_col - gripper_depth * z_col   (raw w, pre-ReLU)
        const float tx = px + 0.5f * wf * bx - 0.1034f * zx;
        const float ty = py + 0.5f * wf * by - 0.1034f * zy;
        const float tz = pz + 0.5f * wf * bz - 0.1034f * zz;

        // grasp 4x4 row-major: row i = [x_i, y_i, z_i, t_i], bottom row [0,0,0,1]
        floatx4 g0, g1, g2, g3;
        g0[0] = bx;  g0[1] = yx;  g0[2] = zx;  g0[3] = tx;
        g1[0] = by;  g1[1] = yy;  g1[2] = zy;  g1[3] = ty;
        g2[0] = bz;  g2[1] = yz;  g2[2] = zz;  g2[3] = tz;
        g3[0] = 0.f; g3[1] = 0.f; g3[2] = 0.f; g3[3] = 1.f;

        // swizzled stage: logical slot k of thread tid lives at tid*4 + (k ^ sw).
        // Per-instruction bank-group = 4*(tid&1) + (k ^ ((tid>>1)&3)) covers all 8
        // float4 bank-groups across any 8 consecutive lanes -> conflict-free b128.
        const int sw = (tid >> 1) & 3;
        lds_g[tid * 4 + (0 ^ sw)] = g0;
        lds_g[tid * 4 + (1 ^ sw)] = g1;
        lds_g[tid * 4 + (2 ^ sw)] = g2;
        lds_g[tid * 4 + (3 ^ sw)] = g3;

        __syncthreads();

        // cooperative coalesced store of 256 grasps (1024 float4, 16KB)
        const long gb = GRASP_BASE4 + bid * 4096 + (long)j * 1024;
#pragma unroll
        for (int k = 0; k < 4; ++k) {
            const int r  = k * 256 + tid;          // logical float4 within the round
            const int tr = r >> 2;                 // owning thread
            const int kr = r & 3;                  // logical slot
            out[gb + r] = lds_g[tr * 4 + (kr ^ ((tr >> 1) & 3))];
        }

        __syncthreads();   // lds_g reads done before next round's staging writes
    }
}

extern "C" void kernel_launch(void* const* d_in, const int* in_sizes, int n_in,
                              void* d_out, int out_size, void* d_ws, size_t ws_size,
                              hipStream_t stream) {
    const floatx4* pts = (const floatx4*)d_in[0];
    const floatx4* z1  = (const floatx4*)d_in[1];
    const floatx4* z2  = (const floatx4*)d_in[2];
    const floatx4* s   = (const floatx4*)d_in[3];
    const floatx4* w   = (const floatx4*)d_in[4];
    floatx4* out = (floatx4*)d_out;

    const int nblocks = (int)(N_POINTS / 1024);   // 4096 blocks x 256 threads
    contactnet_kernel<<<nblocks, 256, 0, stream>>>(pts, z1, z2, s, w, out);
}